// Round 1
// baseline (34545.853 us; speedup 1.0000x reference)
//
#include <hip/hip_runtime.h>
#include <math.h>

#define NBLK   32
#define BS     512
#define NSTATE 17
#define NH     256
#define NX     273      // NH + NSTATE
#define WID    1024
#define NT     64
#define NSUB   8
#define ROWS_H (WID/NBLK)   // 32 rows per block for 1024-wide layers
#define ROWS_L (NH/NBLK)    // 8 rows per block for the 256-wide output layer

typedef unsigned long long u64;

__device__ __forceinline__ float softplus_f(float v) {
    return fmaxf(v, 0.f) + log1pf(expf(-fabsf(v)));
}

// Tagged-word exchange: {round_tag:32 | fp32_bits:32} in one 64-bit word.
// RELAXED AGENT atomics: write-through to the coherence point, bypass L1/L2
// on load. The tag IS the synchronization: consumer spins until tag==round,
// value arrives in the same load. No fences anywhere.
__device__ __forceinline__ void st_tag(u64* p, float v, unsigned R) {
    u64 w = ((u64)R << 32) | (u64)__float_as_uint(v);
    __hip_atomic_store(p, w, __ATOMIC_RELAXED, __HIP_MEMORY_SCOPE_AGENT);
}
__device__ __forceinline__ u64 ld_tag(const u64* p) {
    return __hip_atomic_load(p, __ATOMIC_RELAXED, __HIP_MEMORY_SCOPE_AGENT);
}

// Poll the 1024-word tagged buffer into LDS. Thread t owns {t, t+512}.
__device__ __forceinline__ void poll_z(const u64* __restrict__ buf, unsigned R,
                                       float* __restrict__ z_s, int t) {
    u64 w0 = 0, w1 = 0;
    unsigned done = 0;
    while (done != 3u) {
        if (!(done & 1u)) { w0 = ld_tag(buf + t);       if ((unsigned)(w0 >> 32) == R) done |= 1u; }
        if (!(done & 2u)) { w1 = ld_tag(buf + t + 512); if ((unsigned)(w1 >> 32) == R) done |= 2u; }
    }
    z_s[t]       = __uint_as_float((unsigned)w0);
    z_s[t + 512] = __uint_as_float((unsigned)w1);
    __syncthreads();
}

extern "C" __global__ __launch_bounds__(BS, 1) void ode_kernel(
    const float* __restrict__ ts,   const float* __restrict__ W0,
    const float* __restrict__ b0,   const float* __restrict__ Wh,
    const float* __restrict__ bh,   const float* __restrict__ Wl,
    const float* __restrict__ bl,   const float* __restrict__ betaW,
    const float* __restrict__ betab,const float* __restrict__ hvec,
    const float* __restrict__ scale,const float* __restrict__ y0log,
    float* __restrict__ out, u64* zA, u64* zB, u64* dhb)
{
    const int t   = threadIdx.x;
    const int blk = blockIdx.x;

    __shared__ float y_s[NX];
    __shared__ float yn_s[NX];
    __shared__ float xm[NX];     // MLP-ordered input: [h(256), state(17)]
    __shared__ float k_s[NX];
    __shared__ float z_s[WID];
    __shared__ float red[8];
    __shared__ float dt_sh;

    const float scale0 = scale[0];
    const float betab0 = betab[0];
    unsigned R = 0;   // global exchange round; identical sequence on all blocks

    const int rowH = t >> 4, laneH = t & 15;
    const int growH = blk * ROWS_H + rowH;
    const int rowL = t >> 6, laneL = t & 63;
    const int growL = blk * ROWS_L + rowL;

    // hoisted per-thread constants (loop-invariant)
    const float b0r    = b0[growH];
    float bhr[3];
    bhr[0] = bh[growH]; bhr[1] = bh[WID + growH]; bhr[2] = bh[2 * WID + growH];
    const float blr    = bl[growL];
    const float betaWr = (t < NH) ? betaW[t] : 0.f;
    const float* wh0p = Wh + (size_t)growH * WID + laneH * 4;
    const float* wh1p = wh0p + (size_t)WID * WID;
    const float* wh2p = wh1p + (size_t)WID * WID;
    const float* wlp  = Wl + (size_t)growL * WID + laneL * 4;
    const float* w0p  = W0 + (size_t)growH * NX;

    // ---- y0 = [softmax(y0_log), hvec] ----
    if (t < NSTATE) {
        float m = -1e30f;
        for (int j = 0; j < NSTATE; j++) m = fmaxf(m, y0log[j]);
        float ssum = 0.f;
        for (int j = 0; j < NSTATE; j++) ssum += expf(y0log[j] - m);
        y_s[t] = expf(y0log[t] - m) / ssum;
    }
    if (t < NH) y_s[NSTATE + t] = hvec[t];
    __syncthreads();

    if (blk == 0) {
        if (t < NSTATE) out[t] = y_s[t];
        if (t < NH)     out[NT * NSTATE + t] = y_s[NSTATE + t];
    }

    const float c_xi = 13.f / 12.f, c_mu = 0.041f / 12.f, c_sig = 91.f / 12.f,
                c_nu = 36.f / 12.f, c_gam = 1.8f / 12.f;

    u64* zp[2] = { zA, zB };

    for (int iv = 0; iv < NT - 1; iv++) {
        if (t == 0) dt_sh = (ts[iv + 1] - ts[iv]) * (1.f / NSUB);
        __syncthreads();
        const float dt = dt_sh;

        for (int sub = 0; sub < NSUB; sub++) {
            if (t < NX) yn_s[t] = y_s[t];

            for (int s = 0; s < 4; s++) {
                const float a   = (s == 0) ? 0.f : ((s == 3) ? 1.f : 0.5f);
                const float wgt = ((s == 0) || (s == 3)) ? dt * (1.f / 6.f) : dt * (1.f / 3.f);

                // ---- stage input, built directly in MLP order [h, state] ----
                if (t < NX) {
                    const int src = (t < NH) ? (NSTATE + t) : (t - NH);
                    float v = y_s[src];
                    if (s != 0) v += a * dt * k_s[src];
                    xm[t] = v;
                }
                __syncthreads();

                // ---- L0: 1024x273, 32 rows/block, 16 lanes/row ----
                {
                    float acc = 0.f;
                    for (int c = laneH; c < NX; c += 16) acc += w0p[c] * xm[c];
                    #pragma unroll
                    for (int m = 1; m < 16; m <<= 1) acc += __shfl_xor(acc, m, 16);
                    ++R;
                    if (laneH == 0) st_tag(&zA[growH], softplus_f(acc + b0r), R);
                }

                // ---- prefetch h1 weights; overlaps the zA exchange ----
                float4 wv[16];
                #pragma unroll
                for (int i = 0; i < 16; i++) wv[i] = *(const float4*)(wh0p + i * 64);

                // ---- beta head + dstate: moved OFF the critical path ----
                // (runs after our L0 rows are already published; hides under
                //  the zA store-propagation window)
                {
                    float p = 0.f;
                    if (t < NH) {
                        p = betaWr * xm[t];
                        #pragma unroll
                        for (int m = 1; m < 64; m <<= 1) p += __shfl_xor(p, m, 64);
                        if ((t & 63) == 0) red[t >> 6] = p;
                    }
                    __syncthreads();
                    if (t == 0) {
                        const float* xs = xm + NH;
                        float sd  = red[0] + red[1] + red[2] + red[3] + betab0;
                        float bb1 = 8.f / (1.f + expf(-sd)) + 25.f;
                        float bb2 = 0.5f * bb1, bb3 = 0.35f * bb1, bb4 = 0.25f * bb1;
                        float M  = xs[0],  S1 = xs[1],  E1 = xs[2],  E2 = xs[3];
                        float E3 = xs[4],  E4 = xs[5],  I1 = xs[6],  I2 = xs[7];
                        float I3 = xs[8],  I4 = xs[9],  R1 = xs[10], R2 = xs[11];
                        float R3 = xs[12], R4 = xs[13], S2 = xs[14], S3 = xs[15];
                        float S4 = xs[16];
                        float I = I1 + I2 + I3 + I4, Rs = R1 + R2 + R3 + R4;
                        k_s[0]  = Rs * c_mu - (c_xi + c_mu) * M;
                        k_s[1]  = c_mu * (1.f - Rs) + c_xi * M - c_mu * S1 - bb1 * I * S1;
                        k_s[2]  = bb1 * I * S1 - (c_mu + c_sig) * E1;
                        k_s[3]  = bb2 * I * S2 - (c_mu + c_sig) * E2;
                        k_s[4]  = bb3 * I * S3 - (c_mu + c_sig) * E3;
                        k_s[5]  = bb4 * I * S4 - (c_mu + c_sig) * E4;
                        k_s[6]  = c_sig * E1 - (c_nu + c_mu) * I1;
                        k_s[7]  = c_sig * E2 - (c_nu + c_mu) * I2;
                        k_s[8]  = c_sig * E3 - (c_nu + c_mu) * I3;
                        k_s[9]  = c_sig * E4 - (c_nu + c_mu) * I4;
                        k_s[10] = c_nu * I1 - (c_mu + c_gam) * R1;
                        k_s[11] = c_nu * I2 - (c_mu + c_gam) * R2;
                        k_s[12] = c_nu * I3 - (c_mu + c_gam) * R3;
                        k_s[13] = c_nu * I4 - (c_mu + c_gam) * R4;
                        k_s[14] = c_gam * R1 - c_mu * S2 - bb2 * I * S2;
                        k_s[15] = c_gam * R2 - c_mu * S3 - bb3 * I * S3;
                        k_s[16] = c_gam * (R3 + R4) - c_mu * S4 - bb4 * I * S4;
                    }
                    // no extra barrier: k_s[0..16] is next read only after the
                    // h1 poll barrier (and later ones) have been crossed.
                }

                // ---- hidden layers 1..3: 1024x1024, rotated weight prefetch ----
                float4 wvL[4];
                int cur = 0;
                #pragma unroll
                for (int l = 0; l < 3; l++) {
                    poll_z(zp[cur], R, z_s, t);
                    float acc = 0.f;
                    #pragma unroll
                    for (int i = 0; i < 16; i++) {
                        float4 zv = *(const float4*)(z_s + (laneH * 4 + i * 64));
                        acc += wv[i].x * zv.x + wv[i].y * zv.y + wv[i].z * zv.z + wv[i].w * zv.w;
                    }
                    // prefetch next layer's weights; overlaps our store + next poll
                    if (l < 2) {
                        const float* np = (l == 0) ? wh1p : wh2p;
                        #pragma unroll
                        for (int i = 0; i < 16; i++) wv[i] = *(const float4*)(np + i * 64);
                    } else {
                        #pragma unroll
                        for (int i = 0; i < 4; i++) wvL[i] = *(const float4*)(wlp + i * 256);
                    }
                    #pragma unroll
                    for (int m = 1; m < 16; m <<= 1) acc += __shfl_xor(acc, m, 16);
                    ++R;
                    if (laneH == 0)
                        st_tag(&zp[cur ^ 1][growH], softplus_f(acc + bhr[l]), R);
                    cur ^= 1;
                }

                // ---- Wl: 256x1024, 8 rows/block, 64 lanes/row; tanh epilogue ----
                {
                    poll_z(zp[cur], R, z_s, t);   // h3 lives in zB
                    float acc = 0.f;
                    #pragma unroll
                    for (int i = 0; i < 4; i++) {
                        float4 zv = *(const float4*)(z_s + (laneL * 4 + i * 256));
                        acc += wvL[i].x * zv.x + wvL[i].y * zv.y + wvL[i].z * zv.z + wvL[i].w * zv.w;
                    }
                    #pragma unroll
                    for (int m = 1; m < 64; m <<= 1) acc += __shfl_xor(acc, m, 64);
                    ++R;
                    if (laneL == 0)
                        st_tag(&dhb[growL], scale0 * tanhf(0.01f * (acc + blr)), R);
                }

                // ---- gather dh (tagged poll, one word per thread t<256) ----
                {
                    if (t < NH) {
                        u64 w;
                        do { w = ld_tag(dhb + t); } while ((unsigned)(w >> 32) != R);
                        k_s[NSTATE + t] = __uint_as_float((unsigned)w);
                    }
                    __syncthreads();
                    if (t < NX) yn_s[t] += wgt * k_s[t];
                }
            } // stages

            __syncthreads();
            if (t < NX) y_s[t] = yn_s[t];
            __syncthreads();
        } // substeps

        if (blk == 0) {
            if (t < NSTATE) out[(iv + 1) * NSTATE + t] = y_s[t];
            if (t < NH)     out[NT * NSTATE + (iv + 1) * NH + t] = y_s[NSTATE + t];
        }
    } // intervals
}

extern "C" void kernel_launch(void* const* d_in, const int* in_sizes, int n_in,
                              void* d_out, int out_size, void* d_ws, size_t ws_size,
                              hipStream_t stream) {
    const float* ts    = (const float*)d_in[0];
    const float* W0    = (const float*)d_in[1];
    const float* b0    = (const float*)d_in[2];
    const float* Wh    = (const float*)d_in[3];
    const float* bh    = (const float*)d_in[4];
    const float* Wl    = (const float*)d_in[5];
    const float* bl    = (const float*)d_in[6];
    const float* betaW = (const float*)d_in[7];
    const float* betab = (const float*)d_in[8];
    const float* hvec  = (const float*)d_in[9];
    const float* scale = (const float*)d_in[10];
    const float* y0log = (const float*)d_in[11];
    float* out = (float*)d_out;

    u64* zA  = (u64*)d_ws;                          // 1024*8 = 8 KB
    u64* zB  = (u64*)((char*)d_ws + 8192);          // 8 KB
    u64* dhb = (u64*)((char*)d_ws + 16384);         // 2 KB

    // zero all tags (tag 0 != any R>=1)
    hipMemsetAsync(d_ws, 0, 18432, stream);
    hipLaunchKernelGGL(ode_kernel, dim3(NBLK), dim3(BS), 0, stream,
                       ts, W0, b0, Wh, bh, Wl, bl, betaW, betab, hvec, scale,
                       y0log, out, zA, zB, dhb);
}